// Round 3
// baseline (275.041 us; speedup 1.0000x reference)
//
#include <hip/hip_runtime.h>
#include <hip/hip_bf16.h>

// GNNBackbone: x[B,1000] ⊙ emb[1000,128] -> 3×(GCN+relu) -> mean over D.
// Edges only touch nodes [0,1000) = batch 0. For b>=1 each layer is row-local:
// h <- relu(h@W^T + b), so batches 1..255 run as one fused bf16-MFMA kernel.
// Batch 0 runs the exact f32 agg+gemm chain.
#define B_N 256
#define D_N 1000
#define H_N 128
#define E_N 32000
#define CAP 128   // in-degree capacity (Poisson(32), max ~65 observed)

typedef unsigned int uint32;
typedef unsigned short u16;
typedef __attribute__((ext_vector_type(8))) short bf16x8;
typedef __attribute__((ext_vector_type(4))) float f32x4;

__device__ __forceinline__ u16 f2bf(float f) {
    union { float f; uint32 u; } v; v.f = f;
    return (u16)((v.u + 0x7fffu + ((v.u >> 16) & 1u)) >> 16);  // RNE
}
__device__ __forceinline__ float asf(uint32 u) {
    union { uint32 u; float f; } v; v.u = u; return v.f;
}

// ---------------------------------------------------------------------------
// k_prep: blocks [0,125)  : emb rows (8/block, LDS) -> E1 -> E1h bf16 + t0 f32
//         blocks [125,250): edge pass (deg count + capped edge lists)
//         blocks [250,314): W1/W2 -> bf16
//         blocks [314,442): zero out[256*128]
// deg zeroed by a memset node before this kernel.
// ---------------------------------------------------------------------------
__global__ void k_prep(const float* __restrict__ V, const float* __restrict__ W_embed,
                       const float* __restrict__ b_embed, const int* __restrict__ eidx,
                       const float* __restrict__ W0,
                       const float* __restrict__ Xn, const float* __restrict__ Xc,
                       const float* __restrict__ W1, const float* __restrict__ W2,
                       int* deg, int* __restrict__ es,
                       u16* __restrict__ w1h, u16* __restrict__ w2h,
                       u16* __restrict__ E1h, float* __restrict__ t0,
                       float* __restrict__ out) {
    int bid = blockIdx.x, tid = threadIdx.x;
    if (bid < 125) {
        __shared__ float sEmb[8 * 128];
        int e = tid & 127, h = tid >> 7;
        int d0 = bid * 8 + h * 4;
        // phase A: emb[d0..d0+3][e] = V-row . W_embed-row-e + b_embed[e]
        const float4* wr = (const float4*)(W_embed + e * 300);
        float s0 = b_embed[e], s1 = s0, s2 = s0, s3 = s0;
#pragma unroll 5
        for (int f = 0; f < 75; ++f) {
            float4 w = wr[f];
            float4 v0 = *(const float4*)(V + (d0 + 0) * 300 + f * 4);
            float4 v1 = *(const float4*)(V + (d0 + 1) * 300 + f * 4);
            float4 v2 = *(const float4*)(V + (d0 + 2) * 300 + f * 4);
            float4 v3 = *(const float4*)(V + (d0 + 3) * 300 + f * 4);
            s0 += w.x * v0.x + w.y * v0.y + w.z * v0.z + w.w * v0.w;
            s1 += w.x * v1.x + w.y * v1.y + w.z * v1.z + w.w * v1.w;
            s2 += w.x * v2.x + w.y * v2.y + w.z * v2.z + w.w * v2.w;
            s3 += w.x * v3.x + w.y * v3.y + w.z * v3.z + w.w * v3.w;
        }
        sEmb[(h * 4 + 0) * 128 + e] = s0;
        sEmb[(h * 4 + 1) * 128 + e] = s1;
        sEmb[(h * 4 + 2) * 128 + e] = s2;
        sEmb[(h * 4 + 3) * 128 + e] = s3;
        __syncthreads();
        // phase B: E1[d][e] = emb[d] . W0-row-e
        const float4* w0r = (const float4*)(W0 + e * 128);
        float t[4] = {0.f, 0.f, 0.f, 0.f};
#pragma unroll 8
        for (int k = 0; k < 32; ++k) {
            float4 w = w0r[k];
#pragma unroll
            for (int p = 0; p < 4; ++p) {
                float4 em = *(const float4*)&sEmb[(h * 4 + p) * 128 + k * 4];
                t[p] += w.x * em.x + w.y * em.y + w.z * em.z + w.w * em.w;
            }
        }
#pragma unroll
        for (int p = 0; p < 4; ++p) {
            int d = d0 + p;
            float x0 = (d < 800) ? Xn[d] : Xc[d - 800];
            E1h[d * H_N + e] = f2bf(t[p]);
            t0[d * H_N + e] = x0 * t[p];
        }
    } else if (bid < 250) {
        int i = (bid - 125) * 256 + tid;            // 0..31999 exact
        int s = eidx[i], t = eidx[E_N + i];
        int pos = atomicAdd(&deg[t], 1);
        if (pos < CAP) es[t * CAP + pos] = s;
    } else if (bid < 314) {
        int i = (bid - 250) * 256 + tid;            // 0..16383 exact
        w1h[i] = f2bf(W1[i]); w2h[i] = f2bf(W2[i]);
    } else {
        int i = (bid - 314) * 256 + tid;            // 0..32767 exact
        out[i] = 0.f;
    }
}

// ---------------------------------------------------------------------------
// k_layer: batch-0 GCN layer, fused agg + next GEMM. 1000 blocks x 128.
// dinv recomputed inline from deg (cheap rsqrt).
// ---------------------------------------------------------------------------
__global__ void k_layer(const float* __restrict__ t_in, const float* __restrict__ bias,
                        const float* __restrict__ Wn, const int* __restrict__ deg,
                        const int* __restrict__ es,
                        float* __restrict__ t_out, float* out, int pool) {
    __shared__ float sh[128];
    int d = blockIdx.x, e = threadIdx.x;
    float di = rsqrtf(1.f + (float)deg[d]);
    float acc = t_in[d * H_N + e] * di * di;
    int n = deg[d]; if (n > CAP) n = CAP;
    const int* row = es + d * CAP;
    int i = 0;
    for (; i + 4 <= n; i += 4) {
        int a0 = row[i], a1 = row[i + 1], a2 = row[i + 2], a3 = row[i + 3];
        float c0 = rsqrtf(1.f + (float)deg[a0]);
        float c1 = rsqrtf(1.f + (float)deg[a1]);
        float c2 = rsqrtf(1.f + (float)deg[a2]);
        float c3 = rsqrtf(1.f + (float)deg[a3]);
        acc += di * (c0 * t_in[a0 * H_N + e] + c1 * t_in[a1 * H_N + e] +
                     c2 * t_in[a2 * H_N + e] + c3 * t_in[a3 * H_N + e]);
    }
    for (; i < n; ++i) {
        int s = row[i];
        acc += di * rsqrtf(1.f + (float)deg[s]) * t_in[s * H_N + e];
    }
    float h = acc + bias[e];
    h = h > 0.f ? h : 0.f;
    if (pool) { atomicAdd(&out[e], h * (1.0f / 1000.0f)); return; }
    sh[e] = h;
    __syncthreads();
    const float4* hr = (const float4*)sh;
    const float4* wr = (const float4*)(Wn + e * 128);
    float s = 0.f;
#pragma unroll 8
    for (int k = 0; k < 32; ++k) {
        float4 a = hr[k], w = wr[k];
        s += a.x * w.x + a.y * w.y + a.z * w.z + a.w * w.w;
    }
    t_out[d * H_N + e] = s;
}

// ---------------------------------------------------------------------------
// k_big: batches 1..255, fused 3-layer row-local path.
// 510 blocks (2/batch) x 256 thr, __launch_bounds__(256,2) -> 2 blocks/CU,
// 8 waves/CU, 2 waves/SIMD. LDS = sW1 32KB (shared, swizzled) + sT 32KB
// (per-wave 8KB transpose buf) = exactly 64KB. W2 B-frags stream from
// global (L1/L2-resident 32KB) - no weight VGPR residency, no spills.
// No barriers in the chunk loop (sT wave-private; in-wave DS order suffices).
// MFMA 16x16x32 bf16 (m89/m120-verified layouts):
//   A/B: lane holds M[row=lane&15][k=quad*8+j]; C/D: col=lane&15, row=quad*4+reg
// ---------------------------------------------------------------------------
__device__ __forceinline__ int swz(int row, int col8) {   // u16 idx, granule base
    return row * 128 + ((col8 ^ (row & 7)) << 3);
}

__global__ __launch_bounds__(256, 2)
void k_big(const float* __restrict__ Xn, const float* __restrict__ Xc,
           const u16* __restrict__ E1h, const u16* __restrict__ w1h,
           const u16* __restrict__ w2h, const float* __restrict__ b0,
           const float* __restrict__ b1, const float* __restrict__ b2,
           float* __restrict__ out) {
    __shared__ __align__(16) u16 sW1[128 * 128];     // 32 KiB
    __shared__ __align__(16) u16 sT[4 * 32 * 128];   // 32 KiB (8 KiB/wave)

    const int tid = threadIdx.x;
    const int wave = tid >> 6, lane = tid & 63;
    const int quad = lane >> 4, l15 = lane & 15;
    const int bi = 1 + (blockIdx.x >> 1);
    const int half = blockIdx.x & 1;
    u16* tw = sT + wave * (32 * 128);
    const int odd = l15 & 1;

    // stage W1 into LDS (swizzled granules)
    {
        const uint4* src = (const uint4*)w1h;
        for (int i = tid; i < 2048; i += 256) {
            int row = i >> 4, g = i & 15;
            *(uint4*)&sW1[swz(row, g)] = src[i];
        }
    }

    // biases: b0 per (ks,quad) k-slice; b1/b2 per output col n*16+l15
    float b0v[4][8];
#pragma unroll
    for (int ks = 0; ks < 4; ++ks) {
        float4 lo = *(const float4*)(b0 + (ks * 4 + quad) * 8);
        float4 hi = *(const float4*)(b0 + (ks * 4 + quad) * 8 + 4);
        b0v[ks][0] = lo.x; b0v[ks][1] = lo.y; b0v[ks][2] = lo.z; b0v[ks][3] = lo.w;
        b0v[ks][4] = hi.x; b0v[ks][5] = hi.y; b0v[ks][6] = hi.z; b0v[ks][7] = hi.w;
    }
    float b1g[8], b2g[8];
#pragma unroll
    for (int n = 0; n < 8; ++n) { b1g[n] = b1[n * 16 + l15]; b2g[n] = b2[n * 16 + l15]; }

    __syncthreads();   // sW1 ready; only barrier in the kernel

    float accO[8];
#pragma unroll
    for (int n = 0; n < 8; ++n) accO[n] = 0.f;

    for (int c = 0; c < 4; ++c) {
        int mbase = half * 512 + wave * 128 + c * 32;
        int rA = mbase + l15;      int rAc = rA < D_N ? rA : D_N - 1;
        int rB = rA + 16;          int rBc = rB < D_N ? rB : D_N - 1;
        float xvA = (rAc < 800) ? Xn[bi * 800 + rAc] : Xc[bi * 200 + rAc - 800];
        float xvB = (rBc < 800) ? Xn[bi * 800 + rBc] : Xc[bi * 200 + rBc - 800];

        uint4 eA[4], eB[4];
#pragma unroll
        for (int ks = 0; ks < 4; ++ks) {
            eA[ks] = *(const uint4*)(E1h + rAc * H_N + (ks * 4 + quad) * 8);
            eB[ks] = *(const uint4*)(E1h + rBc * H_N + (ks * 4 + quad) * 8);
        }

        f32x4 acc0[8], acc1[8];
#pragma unroll
        for (int n = 0; n < 8; ++n) {
            acc0[n][0] = 0.f; acc0[n][1] = 0.f; acc0[n][2] = 0.f; acc0[n][3] = 0.f;
            acc1[n][0] = 0.f; acc1[n][1] = 0.f; acc1[n][2] = 0.f; acc1[n][3] = 0.f;
        }

        // ---- GEMM1: h2 = relu(x*E1 + b0) @ W1^T  (B from LDS) ----
#pragma unroll
        for (int ks = 0; ks < 4; ++ks) {
            const uint32* pA = (const uint32*)&eA[ks];
            const uint32* pB = (const uint32*)&eB[ks];
            bf16x8 aA, aB;
#pragma unroll
            for (int p = 0; p < 4; ++p) {
                uint32 uA = pA[p], uB = pB[p];
                float hA0 = fmaf(xvA, asf(uA << 16), b0v[ks][2 * p]);
                float hA1 = fmaf(xvA, asf(uA & 0xffff0000u), b0v[ks][2 * p + 1]);
                float hB0 = fmaf(xvB, asf(uB << 16), b0v[ks][2 * p]);
                float hB1 = fmaf(xvB, asf(uB & 0xffff0000u), b0v[ks][2 * p + 1]);
                hA0 = hA0 > 0.f ? hA0 : 0.f;  hA1 = hA1 > 0.f ? hA1 : 0.f;
                hB0 = hB0 > 0.f ? hB0 : 0.f;  hB1 = hB1 > 0.f ? hB1 : 0.f;
                aA[2 * p] = (short)f2bf(hA0); aA[2 * p + 1] = (short)f2bf(hA1);
                aB[2 * p] = (short)f2bf(hB0); aB[2 * p + 1] = (short)f2bf(hB1);
            }
#pragma unroll
            for (int n = 0; n < 8; ++n) {
                bf16x8 bw = *(const bf16x8*)&sW1[swz(n * 16 + l15, ks * 4 + quad)];
                acc0[n] = __builtin_amdgcn_mfma_f32_16x16x32_bf16(aA, bw, acc0[n], 0, 0, 0);
                acc1[n] = __builtin_amdgcn_mfma_f32_16x16x32_bf16(aB, bw, acc1[n], 0, 0, 0);
            }
        }

        // ---- +b1, relu, pair-packed transpose into wave-private LDS ----
#pragma unroll
        for (int rt = 0; rt < 2; ++rt) {
#pragma unroll
            for (int n = 0; n < 8; ++n) {
                f32x4 a = rt ? acc1[n] : acc0[n];
                float v0 = a[0] + b1g[n]; v0 = v0 > 0.f ? v0 : 0.f;
                float v1 = a[1] + b1g[n]; v1 = v1 > 0.f ? v1 : 0.f;
                float v2 = a[2] + b1g[n]; v2 = v2 > 0.f ? v2 : 0.f;
                float v3 = a[3] + b1g[n]; v3 = v3 > 0.f ? v3 : 0.f;
                float t0_ = __shfl_xor(v0, 1), t1_ = __shfl_xor(v1, 1);
                float t2_ = __shfl_xor(v2, 1), t3_ = __shfl_xor(v3, 1);
                float lo0 = odd ? t2_ : v0, hi0 = odd ? v2 : t0_;
                float lo1 = odd ? t3_ : v1, hi1 = odd ? v3 : t1_;
                int r0 = rt * 16 + quad * 4 + (odd ? 2 : 0);
                int ce = n * 16 + (l15 & ~1);
                uint32 p0 = (uint32)f2bf(lo0) | ((uint32)f2bf(hi0) << 16);
                uint32 p1 = (uint32)f2bf(lo1) | ((uint32)f2bf(hi1) << 16);
                int base0 = r0 * 128 + (((ce >> 3) ^ (r0 & 7)) << 3) + (ce & 7);
                int r1 = r0 + 1;
                int base1 = r1 * 128 + (((ce >> 3) ^ (r1 & 7)) << 3) + (ce & 7);
                *(uint32*)&tw[base0] = p0;
                *(uint32*)&tw[base1] = p1;
            }
        }

        // ---- GEMM2: h3 = h2 @ W2^T  (A from wave-private LDS, B from global) ----
#pragma unroll
        for (int n = 0; n < 8; ++n) {
            acc0[n][0] = 0.f; acc0[n][1] = 0.f; acc0[n][2] = 0.f; acc0[n][3] = 0.f;
            acc1[n][0] = 0.f; acc1[n][1] = 0.f; acc1[n][2] = 0.f; acc1[n][3] = 0.f;
        }
#pragma unroll
        for (int ks = 0; ks < 4; ++ks) {
            int k8 = ks * 4 + quad;
            int ra = l15, rb = 16 + l15;
            bf16x8 a2A = *(const bf16x8*)&tw[ra * 128 + ((k8 ^ (ra & 7)) << 3)];
            bf16x8 a2B = *(const bf16x8*)&tw[rb * 128 + ((k8 ^ (rb & 7)) << 3)];
#pragma unroll
            for (int n = 0; n < 8; ++n) {
                bf16x8 bw = *(const bf16x8*)(w2h + (n * 16 + l15) * H_N + k8 * 8);
                acc0[n] = __builtin_amdgcn_mfma_f32_16x16x32_bf16(a2A, bw, acc0[n], 0, 0, 0);
                acc1[n] = __builtin_amdgcn_mfma_f32_16x16x32_bf16(a2B, bw, acc1[n], 0, 0, 0);
            }
        }

        // ---- +b2, relu, masked column-sum accumulate ----
        int rem = D_N - mbase;   // >= 8 always
#pragma unroll
        for (int rt = 0; rt < 2; ++rt) {
#pragma unroll
            for (int n = 0; n < 8; ++n) {
                f32x4 a = rt ? acc1[n] : acc0[n];
#pragma unroll
                for (int i = 0; i < 4; ++i) {
                    int row32 = rt * 16 + quad * 4 + i;
                    float v = a[i] + b2g[n];
                    v = v > 0.f ? v : 0.f;
                    if (row32 < rem) accO[n] += v;
                }
            }
        }
    }

    // ---- reduce across quads; one atomicAdd per (n, l15) ----
#pragma unroll
    for (int n = 0; n < 8; ++n) {
        float cs = accO[n];
        cs += __shfl_xor(cs, 16);
        cs += __shfl_xor(cs, 32);
        if (lane < 16) atomicAdd(&out[bi * H_N + n * 16 + l15], cs * (1.0f / 1000.0f));
    }
}

// ---------------------------------------------------------------------------
extern "C" void kernel_launch(void* const* d_in, const int* in_sizes, int n_in,
                              void* d_out, int out_size, void* d_ws, size_t ws_size,
                              hipStream_t stream) {
    const float* Xn = (const float*)d_in[0];
    const float* Xc = (const float*)d_in[1];
    const float* V = (const float*)d_in[2];
    const int* eidx = (const int*)d_in[3];
    const float* W_embed = (const float*)d_in[4];
    const float* b_embed = (const float*)d_in[5];
    const float* W0 = (const float*)d_in[6];
    const float* b0 = (const float*)d_in[7];
    const float* W1 = (const float*)d_in[8];
    const float* b1 = (const float*)d_in[9];
    const float* W2 = (const float*)d_in[10];
    const float* b2 = (const float*)d_in[11];
    float* out = (float*)d_out;

    char* p = (char*)d_ws;
    auto alloc = [&](size_t bytes) -> char* {
        char* r = p;
        p += (bytes + 255) & ~(size_t)255;
        return r;
    };
    u16*   E1h = (u16*)  alloc(D_N * H_N * 2);
    float* t0  = (float*)alloc(D_N * H_N * 4);
    float* t1  = (float*)alloc(D_N * H_N * 4);
    float* t2  = (float*)alloc(D_N * H_N * 4);
    u16*   w1h = (u16*)  alloc(H_N * H_N * 2);
    u16*   w2h = (u16*)  alloc(H_N * H_N * 2);
    int*   deg = (int*)  alloc(D_N * 4);
    int*   es  = (int*)  alloc(D_N * CAP * 4);

    hipMemsetAsync(deg, 0, D_N * 4, stream);

    k_prep<<<dim3(442), dim3(256), 0, stream>>>(V, W_embed, b_embed, eidx, W0,
                                                Xn, Xc, W1, W2, deg, es,
                                                w1h, w2h, E1h, t0, out);
    k_big<<<dim3(510), dim3(256), 0, stream>>>(Xn, Xc, E1h, w1h, w2h, b0, b1, b2, out);
    k_layer<<<dim3(1000), dim3(128), 0, stream>>>(t0, b0, W1, deg, es, t1, out, 0);
    k_layer<<<dim3(1000), dim3(128), 0, stream>>>(t1, b1, W2, deg, es, t2, out, 0);
    k_layer<<<dim3(1000), dim3(128), 0, stream>>>(t2, b2, (const float*)nullptr, deg, es,
                                                  (float*)nullptr, out, 1);
}

// Round 4
// 252.146 us; speedup vs baseline: 1.0908x; 1.0908x over previous
//
#include <hip/hip_runtime.h>
#include <hip/hip_bf16.h>

// GNNBackbone: x[B,1000] ⊙ emb[1000,128] -> 3×(GCN+relu) -> mean over D.
// Edges only touch nodes [0,1000) = batch 0. For b>=1 each layer is row-local:
// h <- relu(h@W^T + b), so batches 1..255 run as one fused bf16-MFMA kernel.
// Batch 0 runs the exact f32 agg+gemm chain (3 small kernels).
#define B_N 256
#define D_N 1000
#define H_N 128
#define E_N 32000
#define CAP 128   // in-degree capacity (Poisson(32), max ~65 observed)

typedef unsigned int uint32;
typedef unsigned short u16;
typedef __attribute__((ext_vector_type(8))) short bf16x8;
typedef __attribute__((ext_vector_type(4))) float f32x4;

__device__ __forceinline__ u16 f2bf(float f) {
    union { float f; uint32 u; } v; v.f = f;
    return (u16)((v.u + 0x7fffu + ((v.u >> 16) & 1u)) >> 16);  // RNE
}
__device__ __forceinline__ float asf(uint32 u) {
    union { uint32 u; float f; } v; v.u = u; return v.f;
}
__device__ __forceinline__ uint32 pk2(float lo, float hi) {   // v_cvt_pk_bf16_f32
    __hip_bfloat162 h = __float22bfloat162_rn(make_float2(lo, hi));
    union { __hip_bfloat162 h; uint32 u; } v; v.h = h; return v.u;
}
__device__ __forceinline__ float rl(float x) { return x > 0.f ? x : 0.f; }

// ---------------------------------------------------------------------------
// k_prep: blocks [0,125)  : emb rows (8/block via LDS) -> E1h bf16 + t0 f32
//         blocks [125,133): edge scan per tgt-range: deg + capped edge lists
//                           (LDS-local counters -> no global memset needed)
//         blocks [133,197): W1/W2 -> bf16
//         blocks [197,325): zero out[256*128]
// ---------------------------------------------------------------------------
__global__ void k_prep(const float* __restrict__ V, const float* __restrict__ W_embed,
                       const float* __restrict__ b_embed, const int* __restrict__ eidx,
                       const float* __restrict__ W0,
                       const float* __restrict__ Xn, const float* __restrict__ Xc,
                       const float* __restrict__ W1, const float* __restrict__ W2,
                       int* __restrict__ deg, int* __restrict__ es,
                       u16* __restrict__ w1h, u16* __restrict__ w2h,
                       u16* __restrict__ E1h, float* __restrict__ t0,
                       float* __restrict__ out) {
    int bid = blockIdx.x, tid = threadIdx.x;
    if (bid < 125) {
        __shared__ float sEmb[8 * 128];
        int e = tid & 127, h = tid >> 7;
        int d0 = bid * 8 + h * 4;
        const float4* wr = (const float4*)(W_embed + e * 300);
        float s0 = b_embed[e], s1 = s0, s2 = s0, s3 = s0;
#pragma unroll 5
        for (int f = 0; f < 75; ++f) {
            float4 w = wr[f];
            float4 v0 = *(const float4*)(V + (d0 + 0) * 300 + f * 4);
            float4 v1 = *(const float4*)(V + (d0 + 1) * 300 + f * 4);
            float4 v2 = *(const float4*)(V + (d0 + 2) * 300 + f * 4);
            float4 v3 = *(const float4*)(V + (d0 + 3) * 300 + f * 4);
            s0 += w.x * v0.x + w.y * v0.y + w.z * v0.z + w.w * v0.w;
            s1 += w.x * v1.x + w.y * v1.y + w.z * v1.z + w.w * v1.w;
            s2 += w.x * v2.x + w.y * v2.y + w.z * v2.z + w.w * v2.w;
            s3 += w.x * v3.x + w.y * v3.y + w.z * v3.z + w.w * v3.w;
        }
        sEmb[(h * 4 + 0) * 128 + e] = s0;
        sEmb[(h * 4 + 1) * 128 + e] = s1;
        sEmb[(h * 4 + 2) * 128 + e] = s2;
        sEmb[(h * 4 + 3) * 128 + e] = s3;
        __syncthreads();
        const float4* w0r = (const float4*)(W0 + e * 128);
        float t[4] = {0.f, 0.f, 0.f, 0.f};
#pragma unroll 8
        for (int k = 0; k < 32; ++k) {
            float4 w = w0r[k];
#pragma unroll
            for (int p = 0; p < 4; ++p) {
                float4 em = *(const float4*)&sEmb[(h * 4 + p) * 128 + k * 4];
                t[p] += w.x * em.x + w.y * em.y + w.z * em.z + w.w * em.w;
            }
        }
#pragma unroll
        for (int p = 0; p < 4; ++p) {
            int d = d0 + p;
            float x0 = (d < 800) ? Xn[d] : Xc[d - 800];
            E1h[d * H_N + e] = f2bf(t[p]);
            t0[d * H_N + e] = x0 * t[p];
        }
    } else if (bid < 133) {
        __shared__ int cnt[125];
        int base = (bid - 125) * 125;
        for (int j = tid; j < 125; j += 256) cnt[j] = 0;
        __syncthreads();
        for (int i = tid; i < E_N; i += 256) {
            int t = eidx[E_N + i];
            unsigned rel = (unsigned)(t - base);
            if (rel < 125u) {
                int pos = atomicAdd(&cnt[rel], 1);
                if (pos < CAP) es[t * CAP + pos] = eidx[i];
            }
        }
        __syncthreads();
        for (int j = tid; j < 125; j += 256) deg[base + j] = cnt[j];
    } else if (bid < 197) {
        int i = (bid - 133) * 256 + tid;            // 0..16383 exact
        w1h[i] = f2bf(W1[i]); w2h[i] = f2bf(W2[i]);
    } else {
        int i = (bid - 197) * 256 + tid;            // 0..32767 exact
        out[i] = 0.f;
    }
}

// ---------------------------------------------------------------------------
// k_layer: batch-0 GCN layer, fused agg + next GEMM. 1000 blocks x 128.
// ---------------------------------------------------------------------------
__global__ void k_layer(const float* __restrict__ t_in, const float* __restrict__ bias,
                        const float* __restrict__ Wn, const int* __restrict__ deg,
                        const int* __restrict__ es,
                        float* __restrict__ t_out, float* out, int pool) {
    __shared__ float sh[128];
    int d = blockIdx.x, e = threadIdx.x;
    float di = rsqrtf(1.f + (float)deg[d]);
    float acc = t_in[d * H_N + e] * di * di;
    int n = deg[d]; if (n > CAP) n = CAP;
    const int* row = es + d * CAP;
    int i = 0;
    for (; i + 4 <= n; i += 4) {
        int a0 = row[i], a1 = row[i + 1], a2 = row[i + 2], a3 = row[i + 3];
        float c0 = rsqrtf(1.f + (float)deg[a0]);
        float c1 = rsqrtf(1.f + (float)deg[a1]);
        float c2 = rsqrtf(1.f + (float)deg[a2]);
        float c3 = rsqrtf(1.f + (float)deg[a3]);
        acc += di * (c0 * t_in[a0 * H_N + e] + c1 * t_in[a1 * H_N + e] +
                     c2 * t_in[a2 * H_N + e] + c3 * t_in[a3 * H_N + e]);
    }
    for (; i < n; ++i) {
        int s = row[i];
        acc += di * rsqrtf(1.f + (float)deg[s]) * t_in[s * H_N + e];
    }
    float h = rl(acc + bias[e]);
    if (pool) { atomicAdd(&out[e], h * (1.0f / 1000.0f)); return; }
    sh[e] = h;
    __syncthreads();
    const float4* hr = (const float4*)sh;
    const float4* wr = (const float4*)(Wn + e * 128);
    float s = 0.f;
#pragma unroll 8
    for (int k = 0; k < 32; ++k) {
        float4 a = hr[k], w = wr[k];
        s += a.x * w.x + a.y * w.y + a.z * w.z + a.w * w.w;
    }
    t_out[d * H_N + e] = s;
}

// ---------------------------------------------------------------------------
// k_big: batches 1..255, fused 3-layer row-local path. 2040 blocks x 256
// (one 128-row chunk per block -> accumulators die early, R0-style register
// discipline: ~90 VGPR, no spills). LDS = sW (W1, 32KB shared) + sH (4x8KB
// per-wave h buffer) = 64KB -> 2 blocks/CU, 8 waves/CU. One __syncthreads.
// GEMM1 B from LDS; GEMM2 B from global w2h (L1-resident, dense 64B lines)
// to balance LDS vs VMEM pipes. h2 transpose: pair-packed b32 writes into
// the wave-private region; in-wave DS ordering makes it barrier-free.
// MFMA 16x16x32 bf16 layouts (m89/m120-verified):
//   A/B: lane holds M[row=lane&15][k=quad*8+j]; C/D: col=lane&15, row=quad*4+reg
// ---------------------------------------------------------------------------
__global__ __launch_bounds__(256, 2)
void k_big(const float* __restrict__ Xn, const float* __restrict__ Xc,
           const u16* __restrict__ E1h, const u16* __restrict__ w1h,
           const u16* __restrict__ w2h, const float* __restrict__ b0,
           const float* __restrict__ b1, const float* __restrict__ b2,
           float* __restrict__ out) {
    __shared__ __align__(16) u16 sW[128 * 128];     // 32 KiB: W1 swizzled
    __shared__ __align__(16) u16 sH[4 * 32 * 128];  // 32 KiB: 8KiB/wave

    const int tid = threadIdx.x;
    const int wave = tid >> 6, lane = tid & 63;
    const int quad = lane >> 4, l15 = lane & 15;
    const int bi = 1 + (blockIdx.x >> 3);
    const int d0 = (blockIdx.x & 7) << 7;
    u16* hw = sH + wave * (32 * 128);

    // ---- stage W1 -> sW (swizzled granules) ----
    {
        const uint4* w1v = (const uint4*)w1h;
#pragma unroll
        for (int i = 0; i < 8; ++i) {
            int idx = tid + i * 256;
            int row = idx >> 4, g = idx & 15;
            *(uint4*)&sW[row * 128 + ((g ^ (row & 7)) << 3)] = w1v[idx];
        }
    }

    // ---- build h1 = relu(x*E1 + b0) for this wave's 32 rows ----
    {
        float4 b0a = *(const float4*)(b0 + l15 * 8);
        float4 b0b = *(const float4*)(b0 + l15 * 8 + 4);
#pragma unroll
        for (int it = 0; it < 8; ++it) {
            int r32 = it * 4 + quad;
            int d = d0 + wave * 32 + r32;
            int dc = d < D_N ? d : D_N - 1;
            float xv = (dc < 800) ? Xn[bi * 800 + dc] : Xc[bi * 200 + dc - 800];
            uint4 eg = *(const uint4*)(E1h + dc * H_N + l15 * 8);
            float v0 = rl(fmaf(xv, asf(eg.x << 16), b0a.x));
            float v1 = rl(fmaf(xv, asf(eg.x & 0xffff0000u), b0a.y));
            float v2 = rl(fmaf(xv, asf(eg.y << 16), b0a.z));
            float v3 = rl(fmaf(xv, asf(eg.y & 0xffff0000u), b0a.w));
            float v4 = rl(fmaf(xv, asf(eg.z << 16), b0b.x));
            float v5 = rl(fmaf(xv, asf(eg.z & 0xffff0000u), b0b.y));
            float v6 = rl(fmaf(xv, asf(eg.w << 16), b0b.z));
            float v7 = rl(fmaf(xv, asf(eg.w & 0xffff0000u), b0b.w));
            uint4 pk = { pk2(v0, v1), pk2(v2, v3), pk2(v4, v5), pk2(v6, v7) };
            *(uint4*)&hw[r32 * 128 + ((l15 ^ (r32 & 7)) << 3)] = pk;
        }
    }

    float b1g[8], b2g[8];
#pragma unroll
    for (int n = 0; n < 8; ++n) { b1g[n] = b1[n * 16 + l15]; b2g[n] = b2[n * 16 + l15]; }

    __syncthreads();   // sW ready (h1 is wave-private; in-wave DS order covers it)

    f32x4 acc[2][8];
#pragma unroll
    for (int rt = 0; rt < 2; ++rt)
#pragma unroll
        for (int n = 0; n < 8; ++n) {
            acc[rt][n][0] = 0.f; acc[rt][n][1] = 0.f;
            acc[rt][n][2] = 0.f; acc[rt][n][3] = 0.f;
        }

    // ---- GEMM1: h2 = h1 @ W1^T (A: own LDS region; B: sW) ----
#pragma unroll
    for (int ks = 0; ks < 4; ++ks) {
        int k8 = ks * 4 + quad;
        int m0 = l15, m1 = 16 + l15;
        bf16x8 a0 = *(const bf16x8*)&hw[m0 * 128 + ((k8 ^ (m0 & 7)) << 3)];
        bf16x8 a1 = *(const bf16x8*)&hw[m1 * 128 + ((k8 ^ (m1 & 7)) << 3)];
#pragma unroll
        for (int n = 0; n < 8; ++n) {
            int br = n * 16 + l15;
            bf16x8 bw = *(const bf16x8*)&sW[br * 128 + ((k8 ^ (br & 7)) << 3)];
            acc[0][n] = __builtin_amdgcn_mfma_f32_16x16x32_bf16(a0, bw, acc[0][n], 0, 0, 0);
            acc[1][n] = __builtin_amdgcn_mfma_f32_16x16x32_bf16(a1, bw, acc[1][n], 0, 0, 0);
        }
    }

    // ---- +b1, relu, pair-packed transpose back into own LDS region ----
    {
        const int odd = l15 & 1;
#pragma unroll
        for (int rt = 0; rt < 2; ++rt)
#pragma unroll
            for (int n = 0; n < 8; ++n) {
                float v0 = rl(acc[rt][n][0] + b1g[n]);
                float v1 = rl(acc[rt][n][1] + b1g[n]);
                float v2 = rl(acc[rt][n][2] + b1g[n]);
                float v3 = rl(acc[rt][n][3] + b1g[n]);
                float t0_ = __shfl_xor(v0, 1), t1_ = __shfl_xor(v1, 1);
                float t2_ = __shfl_xor(v2, 1), t3_ = __shfl_xor(v3, 1);
                float lo0 = odd ? t2_ : v0, hi0 = odd ? v2 : t0_;
                float lo1 = odd ? t3_ : v1, hi1 = odd ? v3 : t1_;
                int r0 = rt * 16 + quad * 4 + (odd ? 2 : 0);
                int r1 = r0 + 1;
                int ce = n * 16 + (l15 & ~1);
                *(uint32*)&hw[r0 * 128 + (((ce >> 3) ^ (r0 & 7)) << 3) + (ce & 7)] = pk2(lo0, hi0);
                *(uint32*)&hw[r1 * 128 + (((ce >> 3) ^ (r1 & 7)) << 3) + (ce & 7)] = pk2(lo1, hi1);
            }
    }

    // ---- GEMM2: h3 = h2 @ W2^T (A: own LDS region; B: global, L1-hot) ----
#pragma unroll
    for (int rt = 0; rt < 2; ++rt)
#pragma unroll
        for (int n = 0; n < 8; ++n) {
            acc[rt][n][0] = 0.f; acc[rt][n][1] = 0.f;
            acc[rt][n][2] = 0.f; acc[rt][n][3] = 0.f;
        }
#pragma unroll
    for (int ks = 0; ks < 4; ++ks) {
        int k8 = ks * 4 + quad;
        int m0 = l15, m1 = 16 + l15;
        bf16x8 a0 = *(const bf16x8*)&hw[m0 * 128 + ((k8 ^ (m0 & 7)) << 3)];
        bf16x8 a1 = *(const bf16x8*)&hw[m1 * 128 + ((k8 ^ (m1 & 7)) << 3)];
#pragma unroll
        for (int n = 0; n < 8; ++n) {
            bf16x8 bw = *(const bf16x8*)(w2h + (n * 16 + l15) * H_N + k8 * 8);
            acc[0][n] = __builtin_amdgcn_mfma_f32_16x16x32_bf16(a0, bw, acc[0][n], 0, 0, 0);
            acc[1][n] = __builtin_amdgcn_mfma_f32_16x16x32_bf16(a1, bw, acc[1][n], 0, 0, 0);
        }
    }

    // ---- +b2, relu, masked column-sum, quad-reduce, one atomic per col ----
    int rem = D_N - d0 - wave * 32;   // >= 8 always
#pragma unroll
    for (int n = 0; n < 8; ++n) {
        float cs = 0.f;
#pragma unroll
        for (int rt = 0; rt < 2; ++rt)
#pragma unroll
            for (int i = 0; i < 4; ++i) {
                int r32 = rt * 16 + quad * 4 + i;
                float v = rl(acc[rt][n][i] + b2g[n]);
                if (r32 < rem) cs += v;
            }
        cs += __shfl_xor(cs, 16);
        cs += __shfl_xor(cs, 32);
        if (lane < 16) atomicAdd(&out[bi * H_N + n * 16 + l15], cs * (1.0f / 1000.0f));
    }
}

// ---------------------------------------------------------------------------
extern "C" void kernel_launch(void* const* d_in, const int* in_sizes, int n_in,
                              void* d_out, int out_size, void* d_ws, size_t ws_size,
                              hipStream_t stream) {
    const float* Xn = (const float*)d_in[0];
    const float* Xc = (const float*)d_in[1];
    const float* V = (const float*)d_in[2];
    const int* eidx = (const int*)d_in[3];
    const float* W_embed = (const float*)d_in[4];
    const float* b_embed = (const float*)d_in[5];
    const float* W0 = (const float*)d_in[6];
    const float* b0 = (const float*)d_in[7];
    const float* W1 = (const float*)d_in[8];
    const float* b1 = (const float*)d_in[9];
    const float* W2 = (const float*)d_in[10];
    const float* b2 = (const float*)d_in[11];
    float* out = (float*)d_out;

    char* p = (char*)d_ws;
    auto alloc = [&](size_t bytes) -> char* {
        char* r = p;
        p += (bytes + 255) & ~(size_t)255;
        return r;
    };
    u16*   E1h = (u16*)  alloc(D_N * H_N * 2);
    float* t0  = (float*)alloc(D_N * H_N * 4);
    float* t1  = (float*)alloc(D_N * H_N * 4);
    float* t2  = (float*)alloc(D_N * H_N * 4);
    u16*   w1h = (u16*)  alloc(H_N * H_N * 2);
    u16*   w2h = (u16*)  alloc(H_N * H_N * 2);
    int*   deg = (int*)  alloc(D_N * 4);
    int*   es  = (int*)  alloc(D_N * CAP * 4);

    k_prep<<<dim3(325), dim3(256), 0, stream>>>(V, W_embed, b_embed, eidx, W0,
                                                Xn, Xc, W1, W2, deg, es,
                                                w1h, w2h, E1h, t0, out);
    k_big<<<dim3(2040), dim3(256), 0, stream>>>(Xn, Xc, E1h, w1h, w2h, b0, b1, b2, out);
    k_layer<<<dim3(1000), dim3(128), 0, stream>>>(t0, b0, W1, deg, es, t1, out, 0);
    k_layer<<<dim3(1000), dim3(128), 0, stream>>>(t1, b1, W2, deg, es, t2, out, 0);
    k_layer<<<dim3(1000), dim3(128), 0, stream>>>(t2, b2, (const float*)nullptr, deg, es,
                                                  (float*)nullptr, out, 1);
}

// Round 5
// 202.361 us; speedup vs baseline: 1.3592x; 1.2460x over previous
//
#include <hip/hip_runtime.h>
#include <hip/hip_bf16.h>

// GNNBackbone: x[B,1000] ⊙ emb[1000,128] -> 3×(GCN+relu) -> mean over D.
// Edges only touch nodes [0,1000) = batch 0. For b>=1 each layer is row-local:
// h <- relu(h@W^T + b), so batches 1..255 run as one fused bf16-MFMA kernel.
// Batch 0 runs the exact f32 agg+gemm chain (3 small kernels).
#define B_N 256
#define D_N 1000
#define H_N 128
#define E_N 32000
#define CAP 128   // in-degree capacity (Poisson(32), max ~65 observed)

typedef unsigned int uint32;
typedef unsigned short u16;
typedef __attribute__((ext_vector_type(8))) short bf16x8;
typedef __attribute__((ext_vector_type(4))) float f32x4;

__device__ __forceinline__ u16 f2bf(float f) {
    union { float f; uint32 u; } v; v.f = f;
    return (u16)((v.u + 0x7fffu + ((v.u >> 16) & 1u)) >> 16);  // RNE
}
__device__ __forceinline__ uint32 pk2(float lo, float hi) {   // v_cvt_pk_bf16_f32
    __hip_bfloat162 h = __float22bfloat162_rn(make_float2(lo, hi));
    union { __hip_bfloat162 h; uint32 u; } v; v.h = h; return v.u;
}
__device__ __forceinline__ float asf(uint32 u) {
    union { uint32 u; float f; } v; v.u = u; return v.f;
}
__device__ __forceinline__ float rl(float x) { return x > 0.f ? x : 0.f; }

// load 8 floats at p (absolute k index kbase), zero-padded past k=300
__device__ __forceinline__ void ld8g(const float* __restrict__ p, int kbase, float v[8]) {
    if (kbase + 8 <= 300) {
        float4 a = *(const float4*)p, b = *(const float4*)(p + 4);
        v[0] = a.x; v[1] = a.y; v[2] = a.z; v[3] = a.w;
        v[4] = b.x; v[5] = b.y; v[6] = b.z; v[7] = b.w;
    } else {
#pragma unroll
        for (int j = 0; j < 8; ++j) v[j] = (kbase + j < 300) ? p[j] : 0.f;
    }
}

// ---------------------------------------------------------------------------
// k_prep: blocks [0,32)  : MFMA two-stage: emb = V@W_embed^T + b_embed (K=300,
//                          bf16, zero-padded), transpose via LDS, then
//                          E1 = emb@W0^T -> E1h (bf16) + t0 = x0⊙E1 (f32).
//                          32 d-rows per block.
//         blocks [32,96) : W1/W2 -> bf16
//         blocks [96,224): zero out[256*128]
//         block  224     : zero deg (edge scatter runs inside k_big)
// ---------------------------------------------------------------------------
__global__ void k_prep(const float* __restrict__ V, const float* __restrict__ W_embed,
                       const float* __restrict__ b_embed, const float* __restrict__ W0,
                       const float* __restrict__ Xn, const float* __restrict__ Xc,
                       const float* __restrict__ W1, const float* __restrict__ W2,
                       int* __restrict__ deg,
                       u16* __restrict__ w1h, u16* __restrict__ w2h,
                       u16* __restrict__ E1h, float* __restrict__ t0,
                       float* __restrict__ out) {
    __shared__ __align__(16) u16 sW0[128 * 128];   // 32 KiB: W0 bf16, swizzled
    __shared__ __align__(16) u16 sWc[128 * 64];    // 16 KiB: W_embed k-chunk
    __shared__ __align__(16) u16 sVc[32 * 64];     //  4 KiB: V k-chunk
    __shared__ __align__(16) u16 sT[32 * 128];     //  8 KiB: emb transpose

    int bid = blockIdx.x, tid = threadIdx.x;
    if (bid >= 32) {
        if (bid < 96) {
            int i = (bid - 32) * 256 + tid;            // 0..16383 exact
            w1h[i] = f2bf(W1[i]); w2h[i] = f2bf(W2[i]);
        } else if (bid < 224) {
            int i = (bid - 96) * 256 + tid;            // 0..32767 exact
            out[i] = 0.f;
        } else {
            for (int j = tid; j < D_N; j += 256) deg[j] = 0;
        }
        return;
    }

    const int wave = tid >> 6, lane = tid & 63;
    const int quad = lane >> 4, l15 = lane & 15;
    const int mt = wave & 1, nh = wave >> 1;       // m-tile (16 rows), n-half (64 cols)
    const int dbase = bid * 32;

    // ---- P0: W0 f32 -> sW0 bf16 (swizzled granules) ----
#pragma unroll
    for (int ii = 0; ii < 8; ++ii) {
        int idx = tid + ii * 256;                  // 2048 granules
        int row = idx >> 4, g = idx & 15;
        float4 a = *(const float4*)(W0 + row * 128 + g * 8);
        float4 b = *(const float4*)(W0 + row * 128 + g * 8 + 4);
        uint4 pk = { pk2(a.x, a.y), pk2(a.z, a.w), pk2(b.x, b.y), pk2(b.z, b.w) };
        *(uint4*)&sW0[row * 128 + ((g ^ (row & 7)) << 3)] = pk;
    }

    // ---- stage A: emb = V @ W_embed^T over 5 k-chunks of 64 ----
    f32x4 accA[4];
#pragma unroll
    for (int n = 0; n < 4; ++n) { accA[n][0] = 0.f; accA[n][1] = 0.f; accA[n][2] = 0.f; accA[n][3] = 0.f; }

    for (int ck = 0; ck < 5; ++ck) {
        int k0 = ck * 64;
        // V chunk [32 rows x 64 k]: thread row=t>>3, seg=t&7 (8 floats each)
        {
            int row = tid >> 3, seg = tid & 7;
            int d = dbase + row; int dc = d < D_N ? d : D_N - 1;
            int kk = k0 + seg * 8;
            float v[8]; ld8g(V + dc * 300 + kk, kk, v);
            uint4 pk = { pk2(v[0], v[1]), pk2(v[2], v[3]), pk2(v[4], v[5]), pk2(v[6], v[7]) };
            *(uint4*)&sVc[row * 64 + ((seg ^ (row & 7)) << 3)] = pk;
        }
        // W_embed chunk [128 rows x 64 k]: thread row=t>>1, half=t&1 (32 floats)
        {
            int row = tid >> 1, half = tid & 1;
#pragma unroll
            for (int gg = 0; gg < 4; ++gg) {
                int g = half * 4 + gg;
                int kk = k0 + g * 8;
                float v[8]; ld8g(W_embed + row * 300 + kk, kk, v);
                uint4 pk = { pk2(v[0], v[1]), pk2(v[2], v[3]), pk2(v[4], v[5]), pk2(v[6], v[7]) };
                *(uint4*)&sWc[row * 64 + ((g ^ (row & 7)) << 3)] = pk;
            }
        }
        __syncthreads();
        // MFMA: 2 k-steps x 4 n-tiles
#pragma unroll
        for (int ksb = 0; ksb < 2; ++ksb) {
            int g = ksb * 4 + quad;
            int ar = mt * 16 + l15;
            bf16x8 av = *(const bf16x8*)&sVc[ar * 64 + ((g ^ (ar & 7)) << 3)];
#pragma unroll
            for (int n = 0; n < 4; ++n) {
                int br = nh * 64 + n * 16 + l15;
                bf16x8 bv = *(const bf16x8*)&sWc[br * 64 + ((g ^ (br & 7)) << 3)];
                accA[n] = __builtin_amdgcn_mfma_f32_16x16x32_bf16(av, bv, accA[n], 0, 0, 0);
            }
        }
        __syncthreads();   // WAR on chunk buffers
    }

    // ---- + b_embed, pair-packed transpose into sT (A-layout for stage B) ----
    {
        const int odd = l15 & 1;
#pragma unroll
        for (int n = 0; n < 4; ++n) {
            float bb = b_embed[nh * 64 + n * 16 + l15];
            float v0 = accA[n][0] + bb, v1 = accA[n][1] + bb;
            float v2 = accA[n][2] + bb, v3 = accA[n][3] + bb;
            float t0_ = __shfl_xor(v0, 1), t1_ = __shfl_xor(v1, 1);
            float t2_ = __shfl_xor(v2, 1), t3_ = __shfl_xor(v3, 1);
            float lo0 = odd ? t2_ : v0, hi0 = odd ? v2 : t0_;
            float lo1 = odd ? t3_ : v1, hi1 = odd ? v3 : t1_;
            int r0 = mt * 16 + quad * 4 + (odd ? 2 : 0);
            int r1 = r0 + 1;
            int ce = nh * 64 + n * 16 + (l15 & ~1);
            *(uint32*)&sT[r0 * 128 + (((ce >> 3) ^ (r0 & 7)) << 3) + (ce & 7)] = pk2(lo0, hi0);
            *(uint32*)&sT[r1 * 128 + (((ce >> 3) ^ (r1 & 7)) << 3) + (ce & 7)] = pk2(lo1, hi1);
        }
    }
    __syncthreads();   // sT + sW0 visible to all

    // ---- stage B: E1 = emb @ W0^T (K=128) ----
    f32x4 accB[4];
#pragma unroll
    for (int n = 0; n < 4; ++n) { accB[n][0] = 0.f; accB[n][1] = 0.f; accB[n][2] = 0.f; accB[n][3] = 0.f; }
#pragma unroll
    for (int ks = 0; ks < 4; ++ks) {
        int g = ks * 4 + quad;
        int ar = mt * 16 + l15;
        bf16x8 av = *(const bf16x8*)&sT[ar * 128 + ((g ^ (ar & 7)) << 3)];
#pragma unroll
        for (int n = 0; n < 4; ++n) {
            int br = nh * 64 + n * 16 + l15;
            bf16x8 bv = *(const bf16x8*)&sW0[br * 128 + ((g ^ (br & 7)) << 3)];
            accB[n] = __builtin_amdgcn_mfma_f32_16x16x32_bf16(av, bv, accB[n], 0, 0, 0);
        }
    }

    // ---- epilogue: E1h bf16 + t0 = x0*E1 (rows d < 1000 only) ----
#pragma unroll
    for (int i = 0; i < 4; ++i) {
        int r = mt * 16 + quad * 4 + i;
        int d = dbase + r;
        if (d < D_N) {
            float x0 = (d < 800) ? Xn[d] : Xc[d - 800];
#pragma unroll
            for (int n = 0; n < 4; ++n) {
                int col = nh * 64 + n * 16 + l15;
                float e1 = accB[n][i];
                E1h[d * H_N + col] = f2bf(e1);
                t0[d * H_N + col] = x0 * e1;
            }
        }
    }
}

// ---------------------------------------------------------------------------
// k_layer: batch-0 GCN layer, fused agg + next GEMM. 1000 blocks x 128.
// ---------------------------------------------------------------------------
__global__ void k_layer(const float* __restrict__ t_in, const float* __restrict__ bias,
                        const float* __restrict__ Wn, const int* __restrict__ deg,
                        const int* __restrict__ es,
                        float* __restrict__ t_out, float* out, int pool) {
    __shared__ float sh[128];
    int d = blockIdx.x, e = threadIdx.x;
    float di = rsqrtf(1.f + (float)deg[d]);
    float acc = t_in[d * H_N + e] * di * di;
    int n = deg[d]; if (n > CAP) n = CAP;
    const int* row = es + d * CAP;
    int i = 0;
    for (; i + 4 <= n; i += 4) {
        int a0 = row[i], a1 = row[i + 1], a2 = row[i + 2], a3 = row[i + 3];
        float c0 = rsqrtf(1.f + (float)deg[a0]);
        float c1 = rsqrtf(1.f + (float)deg[a1]);
        float c2 = rsqrtf(1.f + (float)deg[a2]);
        float c3 = rsqrtf(1.f + (float)deg[a3]);
        acc += di * (c0 * t_in[a0 * H_N + e] + c1 * t_in[a1 * H_N + e] +
                     c2 * t_in[a2 * H_N + e] + c3 * t_in[a3 * H_N + e]);
    }
    for (; i < n; ++i) {
        int s = row[i];
        acc += di * rsqrtf(1.f + (float)deg[s]) * t_in[s * H_N + e];
    }
    float h = rl(acc + bias[e]);
    if (pool) { atomicAdd(&out[e], h * (1.0f / 1000.0f)); return; }
    sh[e] = h;
    __syncthreads();
    const float4* hr = (const float4*)sh;
    const float4* wr = (const float4*)(Wn + e * 128);
    float s = 0.f;
#pragma unroll 8
    for (int k = 0; k < 32; ++k) {
        float4 a = hr[k], w = wr[k];
        s += a.x * w.x + a.y * w.y + a.z * w.z + a.w * w.w;
    }
    t_out[d * H_N + e] = s;
}

// ---------------------------------------------------------------------------
// k_big: blocks [0,2040): batches 1..255, fused 3-layer row-local path
//        (structure unchanged from R3 — ~90 VGPR, no spills, 64KB LDS,
//         2 blocks/CU, one __syncthreads).
//        blocks [2040,2165): edge scatter (coalesced single pass, global
//        atomicAdd on deg zeroed by k_prep) — pipelines across CUs instead
//        of the old 8-block serial scan (~85 µs -> ~3 µs).
// MFMA 16x16x32 bf16 layouts (m89/m120-verified):
//   A/B: lane holds M[row=lane&15][k=quad*8+j]; C/D: col=lane&15, row=quad*4+reg
// ---------------------------------------------------------------------------
__global__ __launch_bounds__(256, 2)
void k_big(const float* __restrict__ Xn, const float* __restrict__ Xc,
           const u16* __restrict__ E1h, const u16* __restrict__ w1h,
           const u16* __restrict__ w2h, const float* __restrict__ b0,
           const float* __restrict__ b1, const float* __restrict__ b2,
           const int* __restrict__ eidx, int* __restrict__ deg,
           int* __restrict__ es, float* __restrict__ out) {
    __shared__ __align__(16) u16 sW[128 * 128];     // 32 KiB: W1 swizzled
    __shared__ __align__(16) u16 sH[4 * 32 * 128];  // 32 KiB: 8KiB/wave

    if (blockIdx.x >= 2040) {
        int e = (blockIdx.x - 2040) * 256 + threadIdx.x;   // 0..31999 exact
        int s = eidx[e], t = eidx[E_N + e];
        int pos = atomicAdd(&deg[t], 1);
        if (pos < CAP) es[t * CAP + pos] = s;
        return;
    }

    const int tid = threadIdx.x;
    const int wave = tid >> 6, lane = tid & 63;
    const int quad = lane >> 4, l15 = lane & 15;
    const int bi = 1 + (blockIdx.x >> 3);
    const int d0 = (blockIdx.x & 7) << 7;
    u16* hw = sH + wave * (32 * 128);

    // ---- stage W1 -> sW (swizzled granules) ----
    {
        const uint4* w1v = (const uint4*)w1h;
#pragma unroll
        for (int i = 0; i < 8; ++i) {
            int idx = tid + i * 256;
            int row = idx >> 4, g = idx & 15;
            *(uint4*)&sW[row * 128 + ((g ^ (row & 7)) << 3)] = w1v[idx];
        }
    }

    // ---- build h1 = relu(x*E1 + b0) for this wave's 32 rows ----
    {
        float4 b0a = *(const float4*)(b0 + l15 * 8);
        float4 b0b = *(const float4*)(b0 + l15 * 8 + 4);
#pragma unroll
        for (int it = 0; it < 8; ++it) {
            int r32 = it * 4 + quad;
            int d = d0 + wave * 32 + r32;
            int dc = d < D_N ? d : D_N - 1;
            float xv = (dc < 800) ? Xn[bi * 800 + dc] : Xc[bi * 200 + dc - 800];
            uint4 eg = *(const uint4*)(E1h + dc * H_N + l15 * 8);
            float v0 = rl(fmaf(xv, asf(eg.x << 16), b0a.x));
            float v1 = rl(fmaf(xv, asf(eg.x & 0xffff0000u), b0a.y));
            float v2 = rl(fmaf(xv, asf(eg.y << 16), b0a.z));
            float v3 = rl(fmaf(xv, asf(eg.y & 0xffff0000u), b0a.w));
            float v4 = rl(fmaf(xv, asf(eg.z << 16), b0b.x));
            float v5 = rl(fmaf(xv, asf(eg.z & 0xffff0000u), b0b.y));
            float v6 = rl(fmaf(xv, asf(eg.w << 16), b0b.z));
            float v7 = rl(fmaf(xv, asf(eg.w & 0xffff0000u), b0b.w));
            uint4 pk = { pk2(v0, v1), pk2(v2, v3), pk2(v4, v5), pk2(v6, v7) };
            *(uint4*)&hw[r32 * 128 + ((l15 ^ (r32 & 7)) << 3)] = pk;
        }
    }

    float b1g[8], b2g[8];
#pragma unroll
    for (int n = 0; n < 8; ++n) { b1g[n] = b1[n * 16 + l15]; b2g[n] = b2[n * 16 + l15]; }

    __syncthreads();   // sW ready (h1 is wave-private; in-wave DS order covers it)

    f32x4 acc[2][8];
#pragma unroll
    for (int rt = 0; rt < 2; ++rt)
#pragma unroll
        for (int n = 0; n < 8; ++n) {
            acc[rt][n][0] = 0.f; acc[rt][n][1] = 0.f;
            acc[rt][n][2] = 0.f; acc[rt][n][3] = 0.f;
        }

    // ---- GEMM1: h2 = h1 @ W1^T (A: own LDS region; B: sW) ----
#pragma unroll
    for (int ks = 0; ks < 4; ++ks) {
        int k8 = ks * 4 + quad;
        int m0 = l15, m1 = 16 + l15;
        bf16x8 a0 = *(const bf16x8*)&hw[m0 * 128 + ((k8 ^ (m0 & 7)) << 3)];
        bf16x8 a1 = *(const bf16x8*)&hw[m1 * 128 + ((k8 ^ (m1 & 7)) << 3)];
#pragma unroll
        for (int n = 0; n < 8; ++n) {
            int br = n * 16 + l15;
            bf16x8 bw = *(const bf16x8*)&sW[br * 128 + ((k8 ^ (br & 7)) << 3)];
            acc[0][n] = __builtin_amdgcn_mfma_f32_16x16x32_bf16(a0, bw, acc[0][n], 0, 0, 0);
            acc[1][n] = __builtin_amdgcn_mfma_f32_16x16x32_bf16(a1, bw, acc[1][n], 0, 0, 0);
        }
    }

    // ---- +b1, relu, pair-packed transpose back into own LDS region ----
    {
        const int odd = l15 & 1;
#pragma unroll
        for (int rt = 0; rt < 2; ++rt)
#pragma unroll
            for (int n = 0; n < 8; ++n) {
                float v0 = rl(acc[rt][n][0] + b1g[n]);
                float v1 = rl(acc[rt][n][1] + b1g[n]);
                float v2 = rl(acc[rt][n][2] + b1g[n]);
                float v3 = rl(acc[rt][n][3] + b1g[n]);
                float t0_ = __shfl_xor(v0, 1), t1_ = __shfl_xor(v1, 1);
                float t2_ = __shfl_xor(v2, 1), t3_ = __shfl_xor(v3, 1);
                float lo0 = odd ? t2_ : v0, hi0 = odd ? v2 : t0_;
                float lo1 = odd ? t3_ : v1, hi1 = odd ? v3 : t1_;
                int r0 = rt * 16 + quad * 4 + (odd ? 2 : 0);
                int r1 = r0 + 1;
                int ce = n * 16 + (l15 & ~1);
                *(uint32*)&hw[r0 * 128 + (((ce >> 3) ^ (r0 & 7)) << 3) + (ce & 7)] = pk2(lo0, hi0);
                *(uint32*)&hw[r1 * 128 + (((ce >> 3) ^ (r1 & 7)) << 3) + (ce & 7)] = pk2(lo1, hi1);
            }
    }

    // ---- GEMM2: h3 = h2 @ W2^T (A: own LDS region; B: global, L1-hot) ----
#pragma unroll
    for (int rt = 0; rt < 2; ++rt)
#pragma unroll
        for (int n = 0; n < 8; ++n) {
            acc[rt][n][0] = 0.f; acc[rt][n][1] = 0.f;
            acc[rt][n][2] = 0.f; acc[rt][n][3] = 0.f;
        }
#pragma unroll
    for (int ks = 0; ks < 4; ++ks) {
        int k8 = ks * 4 + quad;
        int m0 = l15, m1 = 16 + l15;
        bf16x8 a0 = *(const bf16x8*)&hw[m0 * 128 + ((k8 ^ (m0 & 7)) << 3)];
        bf16x8 a1 = *(const bf16x8*)&hw[m1 * 128 + ((k8 ^ (m1 & 7)) << 3)];
#pragma unroll
        for (int n = 0; n < 8; ++n) {
            bf16x8 bw = *(const bf16x8*)(w2h + (n * 16 + l15) * H_N + k8 * 8);
            acc[0][n] = __builtin_amdgcn_mfma_f32_16x16x32_bf16(a0, bw, acc[0][n], 0, 0, 0);
            acc[1][n] = __builtin_amdgcn_mfma_f32_16x16x32_bf16(a1, bw, acc[1][n], 0, 0, 0);
        }
    }

    // ---- +b2, relu, masked column-sum, quad-reduce, one atomic per col ----
    int rem = D_N - d0 - wave * 32;   // >= 8 always
#pragma unroll
    for (int n = 0; n < 8; ++n) {
        float cs = 0.f;
#pragma unroll
        for (int rt = 0; rt < 2; ++rt)
#pragma unroll
            for (int i = 0; i < 4; ++i) {
                int r32 = rt * 16 + quad * 4 + i;
                float v = rl(acc[rt][n][i] + b2g[n]);
                if (r32 < rem) cs += v;
            }
        cs += __shfl_xor(cs, 16);
        cs += __shfl_xor(cs, 32);
        if (lane < 16) atomicAdd(&out[bi * H_N + n * 16 + l15], cs * (1.0f / 1000.0f));
    }
}

// ---------------------------------------------------------------------------
extern "C" void kernel_launch(void* const* d_in, const int* in_sizes, int n_in,
                              void* d_out, int out_size, void* d_ws, size_t ws_size,
                              hipStream_t stream) {
    const float* Xn = (const float*)d_in[0];
    const float* Xc = (const float*)d_in[1];
    const float* V = (const float*)d_in[2];
    const int* eidx = (const int*)d_in[3];
    const float* W_embed = (const float*)d_in[4];
    const float* b_embed = (const float*)d_in[5];
    const float* W0 = (const float*)d_in[6];
    const float* b0 = (const float*)d_in[7];
    const float* W1 = (const float*)d_in[8];
    const float* b1 = (const float*)d_in[9];
    const float* W2 = (const float*)d_in[10];
    const float* b2 = (const float*)d_in[11];
    float* out = (float*)d_out;

    char* p = (char*)d_ws;
    auto alloc = [&](size_t bytes) -> char* {
        char* r = p;
        p += (bytes + 255) & ~(size_t)255;
        return r;
    };
    u16*   E1h = (u16*)  alloc(D_N * H_N * 2);
    float* t0  = (float*)alloc(D_N * H_N * 4);
    float* t1  = (float*)alloc(D_N * H_N * 4);
    float* t2  = (float*)alloc(D_N * H_N * 4);
    u16*   w1h = (u16*)  alloc(H_N * H_N * 2);
    u16*   w2h = (u16*)  alloc(H_N * H_N * 2);
    int*   deg = (int*)  alloc(D_N * 4);
    int*   es  = (int*)  alloc(D_N * CAP * 4);

    k_prep<<<dim3(225), dim3(256), 0, stream>>>(V, W_embed, b_embed, W0, Xn, Xc,
                                                W1, W2, deg, w1h, w2h, E1h, t0, out);
    k_big<<<dim3(2165), dim3(256), 0, stream>>>(Xn, Xc, E1h, w1h, w2h, b0, b1, b2,
                                                eidx, deg, es, out);
    k_layer<<<dim3(1000), dim3(128), 0, stream>>>(t0, b0, W1, deg, es, t1, out, 0);
    k_layer<<<dim3(1000), dim3(128), 0, stream>>>(t1, b1, W2, deg, es, t2, out, 0);
    k_layer<<<dim3(1000), dim3(128), 0, stream>>>(t2, b2, (const float*)nullptr, deg, es,
                                                  (float*)nullptr, out, 1);
}